// Round 1
// baseline (73.273 us; speedup 1.0000x reference)
//
#include <hip/hip_runtime.h>

#define N   32
#define NN  1024

// One WAVE (64 lanes) per batch element. Lane (ty,tx) owns a 4x4 cell tile in
// registers (interior of a 6x6 block g). Halo = border of g, fetched from the
// 8 neighboring lanes' registers via __shfl (ds_bpermute crossbar; no LDS, no
// fence, no bank conflicts). Edge lanes mask their missing halo to INF.
//
// R7 restructure (this round):
//  * Fast-sweeping 4-ordering cycle: SE -> SW -> NW -> NE, each preceded by a
//    fresh halo EXCHANGE. Direction diversity resolves path segments that are
//    monotone in any quadrant direction within one raster, instead of ~1
//    cell/raster for SW/NE-trending segments under the old SE/NW-only cycle.
//  * Convergence check after EVERY unit. Sound: any zero-change raster that
//    was preceded by a fresh exchange relaxed every cell against CURRENT
//    neighbor values, i.e. verified dist[c] <= dist[n]+w for all (c,n) ->
//    Bellman fixpoint (all values are real path folds >= fixpoint -> equal).
//  * RELAXD min-tree reshaped: the 4 stale (pre-raster) neighbors fold in an
//    ILP-friendly subtree (schedulable from raster start), the fresh same-row
//    Gauss-Seidel value joins LAST. Serial chain per cell drops from 5 to 3
//    dependent VALU ops (fminf -> add -> fminf). min is exact and every
//    candidate remains the same per-path fp fold -> bitwise-identical result.
//
// Exactness: every assigned value is an fp-fold (((0+w)+w)+...) of a source
// path; monotone-decreasing chaotic iteration from INF converges to the
// unique fixpoint = min-over-paths fold = the reference's Dijkstra distances
// bitwise (validated absmax=0 in R1/R3/R4/R5/R6 under five orders; ordering
// of min-reductions does not affect the fixpoint).
// LDS only in the epilogue (pred/path) with the R3-validated
// single-wave __threadfence_block pattern (R2 showed the fence is mandatory).
__global__ __launch_bounds__(64, 1) void dijkstra_path_kernel(
    const float* __restrict__ weights, float* __restrict__ out)
{
    const int b    = blockIdx.x;
    const int lane = threadIdx.x & 63;
    const int ty   = lane >> 3;        // tile row 0..7
    const int tx   = lane & 7;         // tile col 0..7
    const int y0   = ty << 2;          // tile origin (global cell coords)
    const int x0   = tx << 2;

    __shared__ int   pred[NN];         // 4 KB
    __shared__ float pathf[NN];        // 4 KB

    const float INF = __builtin_huge_valf();

    // ---- pathf = 0 ----
    #pragma unroll
    for (int k = 0; k < 16; ++k) pathf[lane + k * 64] = 0.0f;

    // ---- weights tile -> registers (float4 rows) ----
    float w[4][4];
    const float* wb = weights + b * NN;
    #pragma unroll
    for (int i = 0; i < 4; ++i) {
        const float4 v = *(const float4*)(wb + (y0 + i) * N + x0);
        w[i][0] = v.x; w[i][1] = v.y; w[i][2] = v.z; w[i][3] = v.w;
    }

    // ---- register state: 6x6 (interior = my 4x4 tile, border = halo) ----
    float g[6][6];
    #pragma unroll
    for (int i = 0; i < 6; ++i)
        #pragma unroll
        for (int j = 0; j < 6; ++j) g[i][j] = INF;
    if (lane == 0) g[1][1] = 0.0f;     // source (0,0)

    const bool hT = (ty > 0), hB = (ty < 7), hL = (tx > 0), hR = (tx < 7);

    // fetch halo from neighbor lanes' registers; mask off-grid edges to INF
#define EXCHANGE()                                                            \
    {                                                                         \
        float tT[4], tB[4], tL[4], tR[4];                                     \
        _Pragma("unroll")                                                     \
        for (int j = 0; j < 4; ++j) tT[j] = __shfl(g[4][1 + j], lane - 8);    \
        _Pragma("unroll")                                                     \
        for (int j = 0; j < 4; ++j) tB[j] = __shfl(g[1][1 + j], lane + 8);    \
        _Pragma("unroll")                                                     \
        for (int i = 0; i < 4; ++i) tL[i] = __shfl(g[1 + i][4], lane - 1);    \
        _Pragma("unroll")                                                     \
        for (int i = 0; i < 4; ++i) tR[i] = __shfl(g[1 + i][1], lane + 1);    \
        const float cTL = __shfl(g[4][4], lane - 9);                          \
        const float cTR = __shfl(g[4][1], lane - 7);                          \
        const float cBL = __shfl(g[1][4], lane + 7);                          \
        const float cBR = __shfl(g[1][1], lane + 9);                          \
        _Pragma("unroll")                                                     \
        for (int j = 0; j < 4; ++j) {                                         \
            g[0][1 + j] = hT ? tT[j] : INF;                                   \
            g[5][1 + j] = hB ? tB[j] : INF;                                   \
        }                                                                     \
        _Pragma("unroll")                                                     \
        for (int i = 0; i < 4; ++i) {                                         \
            g[1 + i][0] = hL ? tL[i] : INF;                                   \
            g[1 + i][5] = hR ? tR[i] : INF;                                   \
        }                                                                     \
        g[0][0] = (hT && hL) ? cTL : INF;                                     \
        g[0][5] = (hT && hR) ? cTR : INF;                                     \
        g[5][0] = (hB && hL) ? cBL : INF;                                     \
        g[5][5] = (hB && hR) ? cBR : INF;                                     \
    }

    // Direction-specialized 8-neighbor relax for a raster where row i+FI and
    // same-row cell j+FJ are FRESH (already processed this raster) and row
    // i-FI / cell j-FJ are STALE (pre-raster values; includes halo).
    // st: pure-ILP subtree over the 4 stale neighbors (inputs fixed at raster
    //     start -> scheduler hoists them off the critical path).
    // fr: fresh-row min3 (ready when the previous row finishes).
    // Serial Gauss-Seidel chain through g[i][j+FJ]: fminf -> add -> fminf.
#define RELAXD(i, j, FI, FJ)                                                  \
    {                                                                         \
        const float old = g[(i)][(j)];                                        \
        const float fr  = fminf(fminf(g[(i)+(FI)][(j)-1], g[(i)+(FI)][(j)]),  \
                                g[(i)+(FI)][(j)+1]);                          \
        const float st  = fminf(fminf(fminf(g[(i)-(FI)][(j)-1],               \
                                            g[(i)-(FI)][(j)]),                \
                                      g[(i)-(FI)][(j)+1]),                    \
                                g[(i)][(j)-(FJ)]);                            \
        const float nv  = fminf(fminf(st, fr), g[(i)][(j)+(FJ)])              \
                          + w[(i)-1][(j)-1];                                  \
        changed |= (nv < old);                                                \
        g[(i)][(j)] = fminf(old, nv);                                         \
    }

    // ---- relaxation units: EXCHANGE + raster + certify, cycling 4 orders ----
    for (int it = 0; it < 192; ++it) {   // 768 units == old 384-sweep bound
        bool changed;

        // unit: SE raster (i asc, j asc) — fresh: row above, left cell
        EXCHANGE()
        changed = false;
        #pragma unroll
        for (int i = 1; i <= 4; ++i)
            #pragma unroll
            for (int j = 1; j <= 4; ++j) RELAXD(i, j, -1, -1)
        if (!__any((int)changed)) goto solved;

        // unit: SW raster (i asc, j desc) — fresh: row above, right cell
        EXCHANGE()
        changed = false;
        #pragma unroll
        for (int i = 1; i <= 4; ++i)
            #pragma unroll
            for (int j = 4; j >= 1; --j) RELAXD(i, j, -1, +1)
        if (!__any((int)changed)) goto solved;

        // unit: NW raster (i desc, j desc) — fresh: row below, right cell
        EXCHANGE()
        changed = false;
        #pragma unroll
        for (int i = 4; i >= 1; --i)
            #pragma unroll
            for (int j = 4; j >= 1; --j) RELAXD(i, j, +1, +1)
        if (!__any((int)changed)) goto solved;

        // unit: NE raster (i desc, j asc) — fresh: row below, left cell
        EXCHANGE()
        changed = false;
        #pragma unroll
        for (int i = 4; i >= 1; --i)
            #pragma unroll
            for (int j = 1; j <= 4; ++j) RELAXD(i, j, +1, -1)
        if (!__any((int)changed)) goto solved;
    }
solved:
#undef RELAXD
#undef EXCHANGE

    // ---- predecessors: argmin over 8 neighbors of fp(dist_u + w_v), DIRS order ----
    // (halo in g is fresh: fetched before the zero-change certifying raster)
    {
        const int dy[8] = {-1, 1, 0, 0, -1, -1, 1, 1};
        const int dx[8] = { 0, 0,-1, 1, -1,  1,-1, 1};
        #pragma unroll
        for (int i = 0; i < 4; ++i)
            #pragma unroll
            for (int j = 0; j < 4; ++j) {
                const int yy = y0 + i, xx = x0 + j;
                const int t  = yy * N + xx;
                int p = 0;
                if (t != 0) {
                    float best = INF;
                    #pragma unroll
                    for (int k = 0; k < 8; ++k) {
                        const float u = g[1 + i + dy[k]][1 + j + dx[k]];  // OOB -> INF
                        const float c = u + w[i][j];
                        if (c < best) { best = c; p = (yy + dy[k]) * N + (xx + dx[k]); }
                    }
                }
                pred[t] = p;
            }
    }
    __threadfence_block();             // publish pred (compiler fence; wave DS in-order)

    // ---- serial backtrack from (31,31); pred[0]==0 is the fixed point ----
    if (lane == 0) {
        int cur = NN - 1;
        pathf[cur] = 1.0f;
        for (int s = 0; s < NN && cur != 0; ++s) {
            cur = pred[cur];
            pathf[cur] = 1.0f;
        }
    }
    __threadfence_block();             // publish lane 0's path writes

    // ---- write output (float4 rows) ----
    float* ob = out + b * NN;
    #pragma unroll
    for (int i = 0; i < 4; ++i) {
        const int t = (y0 + i) * N + x0;
        const float4 v = *(const float4*)&pathf[t];
        *(float4*)(ob + t) = v;
    }
}

extern "C" void kernel_launch(void* const* d_in, const int* in_sizes, int n_in,
                              void* d_out, int out_size, void* d_ws, size_t ws_size,
                              hipStream_t stream) {
    const float* w = (const float*)d_in[0];
    float* out = (float*)d_out;
    const int b = in_sizes[0] / NN;   // 128
    dijkstra_path_kernel<<<dim3(b), dim3(64), 0, stream>>>(w, out);
}

// Round 2
// 72.026 us; speedup vs baseline: 1.0173x; 1.0173x over previous
//
#include <hip/hip_runtime.h>

#define N   32
#define NN  1024

// One WAVE (64 lanes) per batch element. Lane (ty,tx) owns a 4x4 cell tile in
// registers (interior of a 6x6 block g). Halo = border of g, fetched from the
// 8 neighboring lanes' registers via __shfl (ds_bpermute crossbar; no LDS, no
// fence, no bank conflicts). Edge lanes mask their missing halo to INF.
//
// R8 (this round): ONE exchange per TWO rasters (SE then NW), certify per unit.
//  * Direction-coverage: an SE raster propagates folds through every move with
//    dy=+1 (any dx) or (0,E); NW covers dy=-1 (any dx) and (0,W). Together
//    they cover all 8 move classes, so SW/NE rasters (R7) are redundant —
//    measured R7 == R6 confirms.
//  * In R6/R7 each move-class only advanced across a tile boundary on its
//    matching raster (every 2nd/4th unit). Fusing SE+NW after a single
//    exchange lets BOTH classes cross one boundary per unit: ~2x fewer units
//    for ~1.5x per-unit cost (the raster pair is issue-bound; the exchange is
//    ~40% of a unit). NW runs on post-SE interior values (Gauss-Seidel) and
//    unit-start halo — still a monotone chaotic relaxation, still exact.
//  * Certificate: if no lane changed in EITHER raster, the grid equals its
//    state at the unit-start exchange, so every cell was relaxed against
//    current neighbor values -> Bellman fixpoint everywhere. Exit then.
//
// Exactness: every assigned value is an fp-fold (((0+w)+w)+...) of a source
// path; monotone-decreasing chaotic iteration from INF converges to the
// unique fixpoint = min-over-paths fold = the reference's Dijkstra distances
// bitwise (validated absmax=0 in R1/R3/R4/R5/R6/R7 under six orderings;
// ordering of min-reductions does not affect the fixpoint).
// LDS only in the epilogue (pred/path) with the R3-validated
// single-wave __threadfence_block pattern (R2 showed the fence is mandatory).
__global__ __launch_bounds__(64, 1) void dijkstra_path_kernel(
    const float* __restrict__ weights, float* __restrict__ out)
{
    const int b    = blockIdx.x;
    const int lane = threadIdx.x & 63;
    const int ty   = lane >> 3;        // tile row 0..7
    const int tx   = lane & 7;         // tile col 0..7
    const int y0   = ty << 2;          // tile origin (global cell coords)
    const int x0   = tx << 2;

    __shared__ int   pred[NN];         // 4 KB
    __shared__ float pathf[NN];        // 4 KB

    const float INF = __builtin_huge_valf();

    // ---- pathf = 0 ----
    #pragma unroll
    for (int k = 0; k < 16; ++k) pathf[lane + k * 64] = 0.0f;

    // ---- weights tile -> registers (float4 rows) ----
    float w[4][4];
    const float* wb = weights + b * NN;
    #pragma unroll
    for (int i = 0; i < 4; ++i) {
        const float4 v = *(const float4*)(wb + (y0 + i) * N + x0);
        w[i][0] = v.x; w[i][1] = v.y; w[i][2] = v.z; w[i][3] = v.w;
    }

    // ---- register state: 6x6 (interior = my 4x4 tile, border = halo) ----
    float g[6][6];
    #pragma unroll
    for (int i = 0; i < 6; ++i)
        #pragma unroll
        for (int j = 0; j < 6; ++j) g[i][j] = INF;
    if (lane == 0) g[1][1] = 0.0f;     // source (0,0)

    const bool hT = (ty > 0), hB = (ty < 7), hL = (tx > 0), hR = (tx < 7);

    // fetch halo from neighbor lanes' registers; mask off-grid edges to INF
#define EXCHANGE()                                                            \
    {                                                                         \
        float tT[4], tB[4], tL[4], tR[4];                                     \
        _Pragma("unroll")                                                     \
        for (int j = 0; j < 4; ++j) tT[j] = __shfl(g[4][1 + j], lane - 8);    \
        _Pragma("unroll")                                                     \
        for (int j = 0; j < 4; ++j) tB[j] = __shfl(g[1][1 + j], lane + 8);    \
        _Pragma("unroll")                                                     \
        for (int i = 0; i < 4; ++i) tL[i] = __shfl(g[1 + i][4], lane - 1);    \
        _Pragma("unroll")                                                     \
        for (int i = 0; i < 4; ++i) tR[i] = __shfl(g[1 + i][1], lane + 1);    \
        const float cTL = __shfl(g[4][4], lane - 9);                          \
        const float cTR = __shfl(g[4][1], lane - 7);                          \
        const float cBL = __shfl(g[1][4], lane + 7);                          \
        const float cBR = __shfl(g[1][1], lane + 9);                          \
        _Pragma("unroll")                                                     \
        for (int j = 0; j < 4; ++j) {                                         \
            g[0][1 + j] = hT ? tT[j] : INF;                                   \
            g[5][1 + j] = hB ? tB[j] : INF;                                   \
        }                                                                     \
        _Pragma("unroll")                                                     \
        for (int i = 0; i < 4; ++i) {                                         \
            g[1 + i][0] = hL ? tL[i] : INF;                                   \
            g[1 + i][5] = hR ? tR[i] : INF;                                   \
        }                                                                     \
        g[0][0] = (hT && hL) ? cTL : INF;                                     \
        g[0][5] = (hT && hR) ? cTR : INF;                                     \
        g[5][0] = (hB && hL) ? cBL : INF;                                     \
        g[5][5] = (hB && hR) ? cBR : INF;                                     \
    }

    // Direction-specialized 8-neighbor relax for a raster where row i+FI and
    // same-row cell j+FJ are FRESH (already processed this raster) and row
    // i-FI / cell j-FJ are STALE; stale neighbors fold in an ILP subtree,
    // the freshest same-row value joins last. min is exact and every
    // candidate remains a per-path fp fold -> bitwise-identical fixpoint.
#define RELAXD(i, j, FI, FJ)                                                  \
    {                                                                         \
        const float old = g[(i)][(j)];                                        \
        const float fr  = fminf(fminf(g[(i)+(FI)][(j)-1], g[(i)+(FI)][(j)]),  \
                                g[(i)+(FI)][(j)+1]);                          \
        const float st  = fminf(fminf(fminf(g[(i)-(FI)][(j)-1],               \
                                            g[(i)-(FI)][(j)]),               \
                                      g[(i)-(FI)][(j)+1]),                    \
                                g[(i)][(j)-(FJ)]);                            \
        const float nv  = fminf(fminf(st, fr), g[(i)][(j)+(FJ)])              \
                          + w[(i)-1][(j)-1];                                  \
        changed |= (nv < old);                                                \
        g[(i)][(j)] = fminf(old, nv);                                         \
    }

    // ---- units: EXCHANGE + SE raster + NW raster + certify ----
    for (int it = 0; it < 384; ++it) {
        bool changed = false;
        EXCHANGE()
        // SE raster (i asc, j asc) — fresh: row above, left cell
        #pragma unroll
        for (int i = 1; i <= 4; ++i)
            #pragma unroll
            for (int j = 1; j <= 4; ++j) RELAXD(i, j, -1, -1)
        // NW raster (i desc, j desc) — fresh: row below, right cell;
        // runs on post-SE interior values + unit-start halo
        #pragma unroll
        for (int i = 4; i >= 1; --i)
            #pragma unroll
            for (int j = 4; j >= 1; --j) RELAXD(i, j, +1, +1)
        if (!__any((int)changed)) break;
    }
#undef RELAXD
#undef EXCHANGE

    // ---- predecessors: argmin over 8 neighbors of fp(dist_u + w_v), DIRS order ----
    // (halo in g is fresh: unit-start exchange + zero-change unit => current)
    {
        const int dy[8] = {-1, 1, 0, 0, -1, -1, 1, 1};
        const int dx[8] = { 0, 0,-1, 1, -1,  1,-1, 1};
        #pragma unroll
        for (int i = 0; i < 4; ++i)
            #pragma unroll
            for (int j = 0; j < 4; ++j) {
                const int yy = y0 + i, xx = x0 + j;
                const int t  = yy * N + xx;
                int p = 0;
                if (t != 0) {
                    float best = INF;
                    #pragma unroll
                    for (int k = 0; k < 8; ++k) {
                        const float u = g[1 + i + dy[k]][1 + j + dx[k]];  // OOB -> INF
                        const float c = u + w[i][j];
                        if (c < best) { best = c; p = (yy + dy[k]) * N + (xx + dx[k]); }
                    }
                }
                pred[t] = p;
            }
    }
    __threadfence_block();             // publish pred (compiler fence; wave DS in-order)

    // ---- serial backtrack from (31,31); pred[0]==0 is the fixed point ----
    if (lane == 0) {
        int cur = NN - 1;
        pathf[cur] = 1.0f;
        for (int s = 0; s < NN && cur != 0; ++s) {
            cur = pred[cur];
            pathf[cur] = 1.0f;
        }
    }
    __threadfence_block();             // publish lane 0's path writes

    // ---- write output (float4 rows) ----
    float* ob = out + b * NN;
    #pragma unroll
    for (int i = 0; i < 4; ++i) {
        const int t = (y0 + i) * N + x0;
        const float4 v = *(const float4*)&pathf[t];
        *(float4*)(ob + t) = v;
    }
}

extern "C" void kernel_launch(void* const* d_in, const int* in_sizes, int n_in,
                              void* d_out, int out_size, void* d_ws, size_t ws_size,
                              hipStream_t stream) {
    const float* w = (const float*)d_in[0];
    float* out = (float*)d_out;
    const int b = in_sizes[0] / NN;   // 128
    dijkstra_path_kernel<<<dim3(b), dim3(64), 0, stream>>>(w, out);
}

// Round 4
// 71.389 us; speedup vs baseline: 1.0264x; 1.0089x over previous
//
#include <hip/hip_runtime.h>

#define N   32
#define NN  1024

// One WAVE (64 lanes) per batch element. Lane (ty,tx) owns a 4x4 cell tile in
// registers (interior of a 6x6 block g). Halo = border of g, fetched from the
// 8 neighboring lanes' registers via __shfl (ds_bpermute crossbar; no LDS, no
// fence, no bank conflicts). Edge lanes mask their missing halo to INF.
//
// Sweep schedule (R8, kept): ONE exchange per unit, SE raster then NW raster,
// certify per unit. SE+NW cover all 8 move classes; both classes cross one
// tile boundary per unit. R6/R7/R8 A/B showed the sweep is only ~3-6 us of
// the kernel (20% per-unit cost change -> <0.5 us dur_us change), so R9
// leaves it alone.
//
// R9 (resubmitted unchanged — R3's bench was an infra failure, "container
// failed twice", no compile/launch evidence against the source):
// accelerate the serial backtrack, the largest single kernel component
// (~4-5.5 us: one dependent ~125cy LDS read per path node, path hop count
// ~80-100 worst-of-128).
//  * After pred[] is final, all 64 lanes cooperatively build
//    pred2[t] = pred[pred[t]] (16 cells/lane; 16 independent first-level
//    reads pipeline, then 16 second-level -> ~2 latencies total, ~450cy).
//  * Lane 0 then chases with TWO INDEPENDENT reads per step (pred[cur] and
//    pred2[cur] issue together, single waitcnt) marking 2 nodes per ~140cy
//    instead of 1 per ~130cy — ~2x on the chase's serial chain.
//  * Marked node set is identical ({pred^m(1023)} for m>=0, plus 1023):
//    pathf output bitwise unchanged. pred[0]==0 => pred2[0]==0 fixed point.
//
// Exactness: every assigned value is an fp-fold (((0+w)+w)+...) of a source
// path; monotone-decreasing chaotic iteration from INF converges to the
// unique fixpoint = min-over-paths fold = the reference's Dijkstra distances
// bitwise (validated absmax=0 in R1/R3/R4/R5/R6/R7/R8 under six orderings).
// LDS epilogue uses the R3-validated single-wave __threadfence_block pattern
// (R2 showed the fence is mandatory); R9 adds one more fence between the
// pred2 build and the chase (same wave-uniform DS-in-order argument).
__global__ __launch_bounds__(64, 1) void dijkstra_path_kernel(
    const float* __restrict__ weights, float* __restrict__ out)
{
    const int b    = blockIdx.x;
    const int lane = threadIdx.x & 63;
    const int ty   = lane >> 3;        // tile row 0..7
    const int tx   = lane & 7;         // tile col 0..7
    const int y0   = ty << 2;          // tile origin (global cell coords)
    const int x0   = tx << 2;

    __shared__ int   pred[NN];         // 4 KB
    __shared__ int   pred2[NN];        // 4 KB (pred^2 jump pointers)
    __shared__ float pathf[NN];        // 4 KB

    const float INF = __builtin_huge_valf();

    // ---- pathf = 0 ----
    #pragma unroll
    for (int k = 0; k < 16; ++k) pathf[lane + k * 64] = 0.0f;

    // ---- weights tile -> registers (float4 rows) ----
    float w[4][4];
    const float* wb = weights + b * NN;
    #pragma unroll
    for (int i = 0; i < 4; ++i) {
        const float4 v = *(const float4*)(wb + (y0 + i) * N + x0);
        w[i][0] = v.x; w[i][1] = v.y; w[i][2] = v.z; w[i][3] = v.w;
    }

    // ---- register state: 6x6 (interior = my 4x4 tile, border = halo) ----
    float g[6][6];
    #pragma unroll
    for (int i = 0; i < 6; ++i)
        #pragma unroll
        for (int j = 0; j < 6; ++j) g[i][j] = INF;
    if (lane == 0) g[1][1] = 0.0f;     // source (0,0)

    const bool hT = (ty > 0), hB = (ty < 7), hL = (tx > 0), hR = (tx < 7);

    // fetch halo from neighbor lanes' registers; mask off-grid edges to INF
#define EXCHANGE()                                                            \
    {                                                                         \
        float tT[4], tB[4], tL[4], tR[4];                                     \
        _Pragma("unroll")                                                     \
        for (int j = 0; j < 4; ++j) tT[j] = __shfl(g[4][1 + j], lane - 8);    \
        _Pragma("unroll")                                                     \
        for (int j = 0; j < 4; ++j) tB[j] = __shfl(g[1][1 + j], lane + 8);    \
        _Pragma("unroll")                                                     \
        for (int i = 0; i < 4; ++i) tL[i] = __shfl(g[1 + i][4], lane - 1);    \
        _Pragma("unroll")                                                     \
        for (int i = 0; i < 4; ++i) tR[i] = __shfl(g[1 + i][1], lane + 1);    \
        const float cTL = __shfl(g[4][4], lane - 9);                          \
        const float cTR = __shfl(g[4][1], lane - 7);                          \
        const float cBL = __shfl(g[1][4], lane + 7);                          \
        const float cBR = __shfl(g[1][1], lane + 9);                          \
        _Pragma("unroll")                                                     \
        for (int j = 0; j < 4; ++j) {                                         \
            g[0][1 + j] = hT ? tT[j] : INF;                                   \
            g[5][1 + j] = hB ? tB[j] : INF;                                   \
        }                                                                     \
        _Pragma("unroll")                                                     \
        for (int i = 0; i < 4; ++i) {                                         \
            g[1 + i][0] = hL ? tL[i] : INF;                                   \
            g[1 + i][5] = hR ? tR[i] : INF;                                   \
        }                                                                     \
        g[0][0] = (hT && hL) ? cTL : INF;                                     \
        g[0][5] = (hT && hR) ? cTR : INF;                                     \
        g[5][0] = (hB && hL) ? cBL : INF;                                     \
        g[5][5] = (hB && hR) ? cBR : INF;                                     \
    }

    // Direction-specialized 8-neighbor relax: stale neighbors fold in an ILP
    // subtree, freshest same-row value joins last. min is exact and every
    // candidate remains a per-path fp fold -> bitwise-identical fixpoint.
#define RELAXD(i, j, FI, FJ)                                                  \
    {                                                                         \
        const float old = g[(i)][(j)];                                        \
        const float fr  = fminf(fminf(g[(i)+(FI)][(j)-1], g[(i)+(FI)][(j)]),  \
                                g[(i)+(FI)][(j)+1]);                          \
        const float st  = fminf(fminf(fminf(g[(i)-(FI)][(j)-1],               \
                                            g[(i)-(FI)][(j)]),               \
                                      g[(i)-(FI)][(j)+1]),                    \
                                g[(i)][(j)-(FJ)]);                            \
        const float nv  = fminf(fminf(st, fr), g[(i)][(j)+(FJ)])              \
                          + w[(i)-1][(j)-1];                                  \
        changed |= (nv < old);                                                \
        g[(i)][(j)] = fminf(old, nv);                                         \
    }

    // ---- units: EXCHANGE + SE raster + NW raster + certify ----
    for (int it = 0; it < 384; ++it) {
        bool changed = false;
        EXCHANGE()
        // SE raster (i asc, j asc) — fresh: row above, left cell
        #pragma unroll
        for (int i = 1; i <= 4; ++i)
            #pragma unroll
            for (int j = 1; j <= 4; ++j) RELAXD(i, j, -1, -1)
        // NW raster (i desc, j desc) — fresh: row below, right cell;
        // runs on post-SE interior values + unit-start halo
        #pragma unroll
        for (int i = 4; i >= 1; --i)
            #pragma unroll
            for (int j = 4; j >= 1; --j) RELAXD(i, j, +1, +1)
        if (!__any((int)changed)) break;
    }
#undef RELAXD
#undef EXCHANGE

    // ---- predecessors: argmin over 8 neighbors of fp(dist_u + w_v), DIRS order ----
    // (halo in g is fresh: unit-start exchange + zero-change unit => current)
    {
        const int dy[8] = {-1, 1, 0, 0, -1, -1, 1, 1};
        const int dx[8] = { 0, 0,-1, 1, -1,  1,-1, 1};
        #pragma unroll
        for (int i = 0; i < 4; ++i)
            #pragma unroll
            for (int j = 0; j < 4; ++j) {
                const int yy = y0 + i, xx = x0 + j;
                const int t  = yy * N + xx;
                int p = 0;
                if (t != 0) {
                    float best = INF;
                    #pragma unroll
                    for (int k = 0; k < 8; ++k) {
                        const float u = g[1 + i + dy[k]][1 + j + dx[k]];  // OOB -> INF
                        const float c = u + w[i][j];
                        if (c < best) { best = c; p = (yy + dy[k]) * N + (xx + dx[k]); }
                    }
                }
                pred[t] = p;
            }
    }
    __threadfence_block();             // publish pred (compiler fence; wave DS in-order)

    // ---- build pred2[t] = pred[pred[t]] cooperatively ----
    // 16 independent first-level reads per lane pipeline; second level waits
    // once. Scattered pred[p1] reads are <=2-way bank aliases (free).
    #pragma unroll
    for (int k = 0; k < 16; ++k) {
        const int t  = lane + k * 64;
        const int p1 = pred[t];
        pred2[t] = pred[p1];
    }
    __threadfence_block();             // publish pred2

    // ---- chase from (31,31): 2 nodes per step via independent pred/pred2 ----
    // Marks {1023} ∪ {pred^m(1023)} — identical node set to the 1-step chase.
    if (lane == 0) {
        int cur = NN - 1;
        pathf[cur] = 1.0f;
        for (int s = 0; s < NN && cur != 0; ++s) {
            const int a  = pred[cur];   // independent reads:
            const int b2 = pred2[cur];  // issue together, one waitcnt
            pathf[a]  = 1.0f;
            pathf[b2] = 1.0f;
            cur = b2;
        }
    }
    __threadfence_block();             // publish lane 0's path writes

    // ---- write output (float4 rows) ----
    float* ob = out + b * NN;
    #pragma unroll
    for (int i = 0; i < 4; ++i) {
        const int t = (y0 + i) * N + x0;
        const float4 v = *(const float4*)&pathf[t];
        *(float4*)(ob + t) = v;
    }
}

extern "C" void kernel_launch(void* const* d_in, const int* in_sizes, int n_in,
                              void* d_out, int out_size, void* d_ws, size_t ws_size,
                              hipStream_t stream) {
    const float* w = (const float*)d_in[0];
    float* out = (float*)d_out;
    const int b = in_sizes[0] / NN;   // 128
    dijkstra_path_kernel<<<dim3(b), dim3(64), 0, stream>>>(w, out);
}